// Round 4
// baseline (1713.877 us; speedup 1.0000x reference)
//
#include <hip/hip_runtime.h>
#include <cstddef>

// HVAE tree decoder, fully fused: one kernel walks the 31-node preorder tree.
// Block = 1 wave = 16 batch rows; grid = B/16 = 1024 (4 blocks/CU).
// h/probs stacks live in LDS (per-block, wave-private => no barriers needed).
// Weights packed B-frag-major bf16 by k_repack; every matmul phase batch-loads
// its B-frags (8-16 in flight) before the MFMA burst to hide L2 latency.

#define BB   16384
#define HH   128
#define OO   32

typedef __attribute__((ext_vector_type(8))) short bf8;
typedef __attribute__((ext_vector_type(4))) float f4;

#define MFMA(a, b, c) __builtin_amdgcn_mfma_f32_16x16x32_bf16(a, b, c, 0, 0, 0)

// packed-weight offsets in ws (shorts)
#define PW_Z2H 0         // [64x128]  -> 8192
#define PW_AWI 8192      // [96x128]  -> 12288
#define PW_AWH 20480     // [384x128] -> 49152
#define PW_FWI 69632     // [96x128]  -> 12288
#define PW_FWH 81920     // [384x128] -> 49152
#define PW_UA  131072    // [128x128] -> 16384
#define PW_UF  147456    // [128x128] -> 16384
#define PW_H2O 163840    // [128x32]  -> 4096
#define PW_END 167936
#define ZBF    167936    // B*64 bf16

#define SH   136   // LDS h row stride (shorts), 16B-aligned rows
#define PSLD 40    // LDS probs row stride (shorts)

__device__ __forceinline__ short f2bf(float f) {
  union { float f; unsigned u; } v; v.f = f;
  unsigned r = v.u + 0x7fff + ((v.u >> 16) & 1);   // RNE
  return (short)(r >> 16);
}
__device__ __forceinline__ float bf2f(short h) {
  union { unsigned u; float f; } v;
  v.u = ((unsigned)(unsigned short)h) << 16;
  return v.f;
}
__device__ __forceinline__ float sigmoidf_(float x) { return 1.0f / (1.0f + __expf(-x)); }
__device__ __forceinline__ float tanhf_(float x) {
  float ax = fabsf(x), e = __expf(-2.0f * ax), t = (1.0f - e) / (1.0f + e);
  return x >= 0.0f ? t : -t;
}

// ---------------- repack: fp32 [K][N] -> B-frag-major bf16 -------------------
// P[((nt*KC + kc)*64 + lane)*8 + j] = W[kc*32 + (lane>>4)*8 + j][nt*16 + (lane&15)]
template <int K, int N>
__device__ __forceinline__ void repack_one(const float* __restrict__ W,
                                           short* __restrict__ P, int idx) {
  const int KC = K / 32;
  const int j = idx & 7, lane = (idx >> 3) & 63, rest = idx >> 9;
  const int kc = rest % KC, nt = rest / KC;
  const int k = kc * 32 + ((lane >> 4) << 3) + j;
  const int n = nt * 16 + (lane & 15);
  P[idx] = f2bf(W[(size_t)k * N + n]);
}

__global__ __launch_bounds__(256) void k_repack(
    const float* __restrict__ z2hw, const float* __restrict__ awi,
    const float* __restrict__ awh, const float* __restrict__ fwi,
    const float* __restrict__ fwh, const float* __restrict__ uaw,
    const float* __restrict__ ufw, const float* __restrict__ h2ow,
    const float* __restrict__ z, short* __restrict__ ws) {
  const int t = blockIdx.x * 256 + threadIdx.x;
  if (t < PW_AWI)        repack_one<64, 128>(z2hw, ws + PW_Z2H, t - PW_Z2H);
  else if (t < PW_AWH)   repack_one<96, 128>(awi, ws + PW_AWI, t - PW_AWI);
  else if (t < PW_FWI)   repack_one<384, 128>(awh, ws + PW_AWH, t - PW_AWH);
  else if (t < PW_FWH)   repack_one<96, 128>(fwi, ws + PW_FWI, t - PW_FWI);
  else if (t < PW_UA)    repack_one<384, 128>(fwh, ws + PW_FWH, t - PW_FWH);
  else if (t < PW_UF)    repack_one<128, 128>(uaw, ws + PW_UA, t - PW_UA);
  else if (t < PW_H2O)   repack_one<128, 128>(ufw, ws + PW_UF, t - PW_UF);
  else if (t < PW_END)   repack_one<128, 32>(h2ow, ws + PW_H2O, t - PW_H2O);
  else {
    const int i = t - PW_END;
    if (i < BB * 64) ws[ZBF + i] = f2bf(z[i]);
  }
}

// ---------------- helpers ---------------------------------------------------
__device__ __forceinline__ void store_h(const f4* hv, short* dst, int l15, int q) {
#pragma unroll
  for (int nt = 0; nt < 8; ++nt)
#pragma unroll
    for (int j = 0; j < 4; ++j)
      dst[(q * 4 + j) * SH + nt * 16 + l15] = f2bf(hv[nt][j]);
}

// GRU for the wave's 16 rows. x from LDS probs row-block (stride PSLD),
// h from LDS h row-block (stride SH). Batched B-frag loads per phase.
__device__ __forceinline__ void gru_lds(const short* xs, const short* hsrc,
                                        const short* wiP, const short* whP,
                                        const float* __restrict__ bi,
                                        const float* __restrict__ bh,
                                        int lane, f4* hv) {
  const int l15 = lane & 15, q = lane >> 4;
  const bf8 ax = *(const bf8*)(xs + l15 * PSLD + q * 8);
  bf8 ah[4];
#pragma unroll
  for (int c = 0; c < 4; ++c)
    ah[c] = *(const bf8*)(hsrc + l15 * SH + c * 32 + q * 8);
  const bf8* wi = (const bf8*)wiP;
  const bf8* wh = (const bf8*)whP;
  f4 t2[8], rg[8];
  // t2 = bh2 + h@wh2
#pragma unroll
  for (int nt = 0; nt < 8; ++nt) {
    const float b = bh[2 * HH + nt * 16 + l15];
    t2[nt] = (f4){b, b, b, b};
  }
#pragma unroll
  for (int h = 0; h < 2; ++h) {
    bf8 W[16];
#pragma unroll
    for (int f = 0; f < 16; ++f)
      W[f] = wh[((f >> 1) * 12 + 8 + h * 2 + (f & 1)) * 64 + lane];
#pragma unroll
    for (int f = 0; f < 16; ++f)
      t2[f >> 1] = MFMA(ah[h * 2 + (f & 1)], W[f], t2[f >> 1]);
  }
  // r-gate preact in rg
#pragma unroll
  for (int nt = 0; nt < 8; ++nt) {
    const float b = bi[nt * 16 + l15] + bh[nt * 16 + l15];
    rg[nt] = (f4){b, b, b, b};
  }
  {
    bf8 Wx[8];
#pragma unroll
    for (int nt = 0; nt < 8; ++nt) Wx[nt] = wi[(nt * 3 + 0) * 64 + lane];
#pragma unroll
    for (int nt = 0; nt < 8; ++nt) rg[nt] = MFMA(ax, Wx[nt], rg[nt]);
  }
#pragma unroll
  for (int h = 0; h < 2; ++h) {
    bf8 W[16];
#pragma unroll
    for (int f = 0; f < 16; ++f)
      W[f] = wh[((f >> 1) * 12 + 0 + h * 2 + (f & 1)) * 64 + lane];
#pragma unroll
    for (int f = 0; f < 16; ++f)
      rg[f >> 1] = MFMA(ah[h * 2 + (f & 1)], W[f], rg[f >> 1]);
  }
#pragma unroll
  for (int nt = 0; nt < 8; ++nt)
#pragma unroll
    for (int j = 0; j < 4; ++j) t2[nt][j] *= sigmoidf_(rg[nt][j]);  // r*(h@wh2+bh2)
  // n preact completes in t2; z preact in rg
#pragma unroll
  for (int nt = 0; nt < 8; ++nt) {
    const float b = bi[2 * HH + nt * 16 + l15];
#pragma unroll
    for (int j = 0; j < 4; ++j) t2[nt][j] += b;
  }
  {
    bf8 Wx[8];
#pragma unroll
    for (int nt = 0; nt < 8; ++nt) Wx[nt] = wi[(nt * 3 + 2) * 64 + lane];
#pragma unroll
    for (int nt = 0; nt < 8; ++nt) t2[nt] = MFMA(ax, Wx[nt], t2[nt]);
  }
#pragma unroll
  for (int nt = 0; nt < 8; ++nt) {
    const float b = bi[HH + nt * 16 + l15] + bh[HH + nt * 16 + l15];
    rg[nt] = (f4){b, b, b, b};
  }
  {
    bf8 Wx[8];
#pragma unroll
    for (int nt = 0; nt < 8; ++nt) Wx[nt] = wi[(nt * 3 + 1) * 64 + lane];
#pragma unroll
    for (int nt = 0; nt < 8; ++nt) rg[nt] = MFMA(ax, Wx[nt], rg[nt]);
  }
#pragma unroll
  for (int h = 0; h < 2; ++h) {
    bf8 W[16];
#pragma unroll
    for (int f = 0; f < 16; ++f)
      W[f] = wh[((f >> 1) * 12 + 4 + h * 2 + (f & 1)) * 64 + lane];
#pragma unroll
    for (int f = 0; f < 16; ++f)
      rg[f >> 1] = MFMA(ah[h * 2 + (f & 1)], W[f], rg[f >> 1]);
  }
  // h' = (1-z)*tanh(n) + z*h
#pragma unroll
  for (int nt = 0; nt < 8; ++nt)
#pragma unroll
    for (int j = 0; j < 4; ++j) {
      const float hc = bf2f(hsrc[(q * 4 + j) * SH + nt * 16 + l15]);
      const float z = sigmoidf_(rg[nt][j]);
      const float n = tanhf_(t2[nt][j]);
      hv[nt][j] = (1.0f - z) * n + z * hc;
    }
}

// pred = h@h2o + b; softmax; pred->global, probs->LDS probs row-block.
__device__ __forceinline__ void pred_node(const short* hsrc,
                                          const short* h2oP,
                                          const float* __restrict__ h2ob,
                                          float* __restrict__ predout,
                                          short* pdst, int r0, int lane) {
  const int l15 = lane & 15, q = lane >> 4;
  bf8 a[4];
#pragma unroll
  for (int c = 0; c < 4; ++c)
    a[c] = *(const bf8*)(hsrc + l15 * SH + c * 32 + q * 8);
  const bf8* bo = (const bf8*)h2oP;
  bf8 W[8];
#pragma unroll
  for (int f = 0; f < 8; ++f) W[f] = bo[f * 64 + lane];
  f4 p[2];
#pragma unroll
  for (int nt = 0; nt < 2; ++nt) {
    const float b = h2ob[nt * 16 + l15];
    f4 acc = (f4){b, b, b, b};
#pragma unroll
    for (int c = 0; c < 4; ++c) acc = MFMA(a[c], W[nt * 4 + c], acc);
    p[nt] = acc;
  }
#pragma unroll
  for (int j = 0; j < 4; ++j) {
    const float v0 = p[0][j], v1 = p[1][j];
    float mx = fmaxf(v0, v1);
#pragma unroll
    for (int s = 1; s < 16; s <<= 1) mx = fmaxf(mx, __shfl_xor(mx, s));
    const float e0 = __expf(v0 - mx), e1 = __expf(v1 - mx);
    float ss = e0 + e1;
#pragma unroll
    for (int s = 1; s < 16; s <<= 1) ss += __shfl_xor(ss, s);
    const float inv = 1.0f / ss;
    const int row = q * 4 + j;
    predout[(size_t)(r0 + row) * OO + l15] = v0;
    predout[(size_t)(r0 + row) * OO + 16 + l15] = v1;
    pdst[row * PSLD + l15] = f2bf(e0 * inv);
    pdst[row * PSLD + 16 + l15] = f2bf(e1 * inv);
  }
}

// preorder schedule, depth 4: type 0=root, 1=left child (gru_a), 2=right child
__device__ const unsigned char d_TYPE[31] =
    {0,1,1,1,1,2,2,1,2,2,1,1,2,2,1,2,2,1,1,1,2,2,1,2,2,1,1,2,2,1,2};
__device__ const unsigned char d_LVL[31] =
    {0,1,2,3,4,4,3,4,4,2,3,4,4,3,4,4,1,2,3,4,4,3,4,4,2,3,4,4,3,4,4};

// ---------------- the fused tree kernel -------------------------------------
__global__ __launch_bounds__(64, 1) void k_tree(
    const short* __restrict__ zbf, const short* __restrict__ pw,
    const float* __restrict__ z2hb, const float* __restrict__ abi,
    const float* __restrict__ abh, const float* __restrict__ fbi,
    const float* __restrict__ fbh, const float* __restrict__ uab,
    const float* __restrict__ ufb, const float* __restrict__ h2ob,
    float* __restrict__ out) {
  __shared__ short hstk[5 * 16 * SH];
  __shared__ short hfb[16 * SH];
  __shared__ short pstk[5 * 16 * PSLD];
  const int lane = threadIdx.x;
  const int l15 = lane & 15, q = lane >> 4;
  const int r0 = blockIdx.x * 16;

  // root: h_in[0] = z @ z2h + b
  {
    const bf8 az0 = *(const bf8*)(zbf + (size_t)(r0 + l15) * 64 + q * 8);
    const bf8 az1 = *(const bf8*)(zbf + (size_t)(r0 + l15) * 64 + 32 + q * 8);
    const bf8* wz = (const bf8*)(pw + PW_Z2H);
    bf8 W[16];
#pragma unroll
    for (int f = 0; f < 16; ++f) W[f] = wz[f * 64 + lane];
    f4 hv[8];
#pragma unroll
    for (int nt = 0; nt < 8; ++nt) {
      const float b = z2hb[nt * 16 + l15];
      f4 acc = (f4){b, b, b, b};
      acc = MFMA(az0, W[nt * 2 + 0], acc);
      acc = MFMA(az1, W[nt * 2 + 1], acc);
      hv[nt] = acc;
    }
    store_h(hv, hstk, l15, q);
  }

#pragma unroll 1
  for (int i = 0; i < 31; ++i) {
    const int t = d_TYPE[i];
    const int L = d_LVL[i];
    short* hcur = hstk + L * 16 * SH;
    short* pcur = pstk + L * 16 * PSLD;

    if (t == 2) {
      // h_f = gru_f(probs_sib, h_sib); h_in[L] = tanh(h_f@uf + h_in[L-1]@ua + b)
      f4 hf[8];
      gru_lds(pcur, hcur, pw + PW_FWI, pw + PW_FWH, fbi, fbh, lane, hf);
      store_h(hf, hfb, l15, q);
      bf8 af[4], ap[4];
      const short* hpar = hstk + (L - 1) * 16 * SH;
#pragma unroll
      for (int c = 0; c < 4; ++c) {
        af[c] = *(const bf8*)(hfb + l15 * SH + c * 32 + q * 8);
        ap[c] = *(const bf8*)(hpar + l15 * SH + c * 32 + q * 8);
      }
      const bf8* uf = (const bf8*)(pw + PW_UF);
      const bf8* ua = (const bf8*)(pw + PW_UA);
      f4 hv[8];
#pragma unroll
      for (int nt = 0; nt < 8; ++nt) {
        const float b = ufb[nt * 16 + l15] + uab[nt * 16 + l15];
        hv[nt] = (f4){b, b, b, b};
      }
#pragma unroll
      for (int h = 0; h < 2; ++h) {
        bf8 Wf[16], Wa[16];
#pragma unroll
        for (int f = 0; f < 16; ++f) {
          Wf[f] = uf[((f >> 1) * 4 + h * 2 + (f & 1)) * 64 + lane];
          Wa[f] = ua[((f >> 1) * 4 + h * 2 + (f & 1)) * 64 + lane];
        }
#pragma unroll
        for (int f = 0; f < 16; ++f) {
          hv[f >> 1] = MFMA(af[h * 2 + (f & 1)], Wf[f], hv[f >> 1]);
          hv[f >> 1] = MFMA(ap[h * 2 + (f & 1)], Wa[f], hv[f >> 1]);
        }
      }
#pragma unroll
      for (int nt = 0; nt < 8; ++nt)
#pragma unroll
        for (int j = 0; j < 4; ++j) hv[nt][j] = tanhf_(hv[nt][j]);
      store_h(hv, hcur, l15, q);
    }

    // pred + softmax (reads hcur, writes out + pcur)
    pred_node(hcur, pw + PW_H2O, h2ob, out + (size_t)i * BB * OO, pcur, r0, lane);

    // non-leaf: h_in[L+1] = gru_a(probs, h_in[L])
    if (L < 4) {
      f4 hv[8];
      gru_lds(pcur, hcur, pw + PW_AWI, pw + PW_AWH, abi, abh, lane, hv);
      store_h(hv, hstk + (L + 1) * 16 * SH, l15, q);
    }
  }
}

// ---------------- host ------------------------------------------------------
extern "C" void kernel_launch(void* const* d_in, const int* in_sizes, int n_in,
                              void* d_out, int out_size, void* d_ws, size_t ws_size,
                              hipStream_t stream) {
  const float* z    = (const float*)d_in[0];
  const float* z2hw = (const float*)d_in[1];
  const float* z2hb = (const float*)d_in[2];
  const float* h2ow = (const float*)d_in[3];
  const float* h2ob = (const float*)d_in[4];
  const float* awi  = (const float*)d_in[5];
  const float* abi  = (const float*)d_in[6];
  const float* awh  = (const float*)d_in[7];
  const float* abh  = (const float*)d_in[8];
  const float* fwi  = (const float*)d_in[9];
  const float* fbi  = (const float*)d_in[10];
  const float* fwh  = (const float*)d_in[11];
  const float* fbh  = (const float*)d_in[12];
  const float* uaw  = (const float*)d_in[13];
  const float* uab  = (const float*)d_in[14];
  const float* ufw  = (const float*)d_in[15];
  const float* ufb  = (const float*)d_in[16];

  float* out = (float*)d_out;
  short* ws  = (short*)d_ws;

  const int total = PW_END + BB * 64;
  k_repack<<<(total + 255) / 256, 256, 0, stream>>>(
      z2hw, awi, awh, fwi, fwh, uaw, ufw, h2ow, z, ws);

  k_tree<<<BB / 16, 64, 0, stream>>>(
      ws + ZBF, ws, z2hb, abi, abh, fbi, fbh, uab, ufb, h2ob, out);
}

// Round 5
// 555.217 us; speedup vs baseline: 3.0869x; 3.0869x over previous
//
#include <hip/hip_runtime.h>
#include <cstddef>

// HVAE tree decoder, fused single kernel. Block = 256 thr (4 waves) = 16 batch
// rows; each wave owns a 32-col slice (2 nt-tiles) of every matmul's N=128.
// h/probs stacks in LDS, block barriers between producer/consumer phases.
// Weights packed B-frag-major bf16 (k_repack); per wave only its slice's
// fragments are loaded (4x fewer than round 4), batched 8-10 in flight.
// __launch_bounds__(256,4) caps VGPR at 128 (no spills), 16 waves/CU.

#define BB   16384
#define HH   128
#define OO   32

typedef __attribute__((ext_vector_type(8))) short bf8;
typedef __attribute__((ext_vector_type(4))) float f4;

#define MFMA(a, b, c) __builtin_amdgcn_mfma_f32_16x16x32_bf16(a, b, c, 0, 0, 0)

// packed-weight offsets in ws (shorts)
#define PW_Z2H 0         // [64x128]  -> 8192
#define PW_AWI 8192      // [96x128]  -> 12288
#define PW_AWH 20480     // [384x128] -> 49152
#define PW_FWI 69632     // [96x128]  -> 12288
#define PW_FWH 81920     // [384x128] -> 49152
#define PW_UA  131072    // [128x128] -> 16384
#define PW_UF  147456    // [128x128] -> 16384
#define PW_H2O 163840    // [128x32]  -> 4096
#define PW_END 167936
#define ZBF    167936    // B*64 bf16

#define SH   136   // LDS h row stride (shorts)
#define PSLD 40    // LDS probs row stride (shorts)

__device__ __forceinline__ short f2bf(float f) {
  union { float f; unsigned u; } v; v.f = f;
  unsigned r = v.u + 0x7fff + ((v.u >> 16) & 1);   // RNE
  return (short)(r >> 16);
}
__device__ __forceinline__ float bf2f(short h) {
  union { unsigned u; float f; } v;
  v.u = ((unsigned)(unsigned short)h) << 16;
  return v.f;
}
__device__ __forceinline__ float sigmoidf_(float x) { return 1.0f / (1.0f + __expf(-x)); }
__device__ __forceinline__ float tanhf_(float x) {
  float ax = fabsf(x), e = __expf(-2.0f * ax), t = (1.0f - e) / (1.0f + e);
  return x >= 0.0f ? t : -t;
}

// ---------------- repack: fp32 [K][N] -> B-frag-major bf16 -------------------
// P[((nt*KC + kc)*64 + lane)*8 + j] = W[kc*32 + (lane>>4)*8 + j][nt*16 + (lane&15)]
template <int K, int N>
__device__ __forceinline__ void repack_one(const float* __restrict__ W,
                                           short* __restrict__ P, int idx) {
  const int KC = K / 32;
  const int j = idx & 7, lane = (idx >> 3) & 63, rest = idx >> 9;
  const int kc = rest % KC, nt = rest / KC;
  const int k = kc * 32 + ((lane >> 4) << 3) + j;
  const int n = nt * 16 + (lane & 15);
  P[idx] = f2bf(W[(size_t)k * N + n]);
}

__global__ __launch_bounds__(256) void k_repack(
    const float* __restrict__ z2hw, const float* __restrict__ awi,
    const float* __restrict__ awh, const float* __restrict__ fwi,
    const float* __restrict__ fwh, const float* __restrict__ uaw,
    const float* __restrict__ ufw, const float* __restrict__ h2ow,
    const float* __restrict__ z, short* __restrict__ ws) {
  const int t = blockIdx.x * 256 + threadIdx.x;
  if (t < PW_AWI)        repack_one<64, 128>(z2hw, ws + PW_Z2H, t - PW_Z2H);
  else if (t < PW_AWH)   repack_one<96, 128>(awi, ws + PW_AWI, t - PW_AWI);
  else if (t < PW_FWI)   repack_one<384, 128>(awh, ws + PW_AWH, t - PW_AWH);
  else if (t < PW_FWH)   repack_one<96, 128>(fwi, ws + PW_FWI, t - PW_FWI);
  else if (t < PW_UA)    repack_one<384, 128>(fwh, ws + PW_FWH, t - PW_FWH);
  else if (t < PW_UF)    repack_one<128, 128>(uaw, ws + PW_UA, t - PW_UA);
  else if (t < PW_H2O)   repack_one<128, 128>(ufw, ws + PW_UF, t - PW_UF);
  else if (t < PW_END)   repack_one<128, 32>(h2ow, ws + PW_H2O, t - PW_H2O);
  else {
    const int i = t - PW_END;
    if (i < BB * 64) ws[ZBF + i] = f2bf(z[i]);
  }
}

// ---------------- slice helpers (wave w owns nt tiles 2w, 2w+1) -------------
__device__ __forceinline__ void store_slice(const f4* hv, short* dst, int lane, int w) {
  const int l15 = lane & 15, q = lane >> 4;
#pragma unroll
  for (int n = 0; n < 2; ++n)
#pragma unroll
    for (int j = 0; j < 4; ++j)
      dst[(q * 4 + j) * SH + (2 * w + n) * 16 + l15] = f2bf(hv[n][j]);
}

// GRU slice: x from LDS probs block, h from LDS h block; out h'[16 x 32] slice.
__device__ __forceinline__ void gru_slice(const short* xs, const short* hsrc,
                                          const short* wiP, const short* whP,
                                          const float* __restrict__ bi,
                                          const float* __restrict__ bh,
                                          int lane, int w, f4* hv) {
  const int l15 = lane & 15, q = lane >> 4;
  const int nt0 = 2 * w;
  const bf8 ax = *(const bf8*)(xs + l15 * PSLD + q * 8);
  bf8 ah[4];
#pragma unroll
  for (int c = 0; c < 4; ++c)
    ah[c] = *(const bf8*)(hsrc + l15 * SH + c * 32 + q * 8);
  const bf8* wi = (const bf8*)wiP;
  const bf8* wh = (const bf8*)whP;
  f4 t2[2], rg[2];
  // t2 = bh2 + h@wh2
#pragma unroll
  for (int n = 0; n < 2; ++n) {
    const float b = bh[2 * HH + (nt0 + n) * 16 + l15];
    t2[n] = (f4){b, b, b, b};
  }
  {
    bf8 W[8];
#pragma unroll
    for (int f = 0; f < 8; ++f)
      W[f] = wh[((nt0 + (f >> 2)) * 12 + 8 + (f & 3)) * 64 + lane];
#pragma unroll
    for (int f = 0; f < 8; ++f) t2[f >> 2] = MFMA(ah[f & 3], W[f], t2[f >> 2]);
  }
  // r gate
#pragma unroll
  for (int n = 0; n < 2; ++n) {
    const float b = bi[(nt0 + n) * 16 + l15] + bh[(nt0 + n) * 16 + l15];
    rg[n] = (f4){b, b, b, b};
  }
  {
    bf8 Wx[2], W[8];
#pragma unroll
    for (int n = 0; n < 2; ++n) Wx[n] = wi[((nt0 + n) * 3 + 0) * 64 + lane];
#pragma unroll
    for (int f = 0; f < 8; ++f)
      W[f] = wh[((nt0 + (f >> 2)) * 12 + 0 + (f & 3)) * 64 + lane];
#pragma unroll
    for (int n = 0; n < 2; ++n) rg[n] = MFMA(ax, Wx[n], rg[n]);
#pragma unroll
    for (int f = 0; f < 8; ++f) rg[f >> 2] = MFMA(ah[f & 3], W[f], rg[f >> 2]);
  }
#pragma unroll
  for (int n = 0; n < 2; ++n)
#pragma unroll
    for (int j = 0; j < 4; ++j) t2[n][j] *= sigmoidf_(rg[n][j]);  // r*(h@wh2+bh2)
  // n preact completes in t2
#pragma unroll
  for (int n = 0; n < 2; ++n) {
    const float b = bi[2 * HH + (nt0 + n) * 16 + l15];
#pragma unroll
    for (int j = 0; j < 4; ++j) t2[n][j] += b;
  }
  {
    bf8 Wx[2];
#pragma unroll
    for (int n = 0; n < 2; ++n) Wx[n] = wi[((nt0 + n) * 3 + 2) * 64 + lane];
#pragma unroll
    for (int n = 0; n < 2; ++n) t2[n] = MFMA(ax, Wx[n], t2[n]);
  }
  // z gate
#pragma unroll
  for (int n = 0; n < 2; ++n) {
    const float b = bi[HH + (nt0 + n) * 16 + l15] + bh[HH + (nt0 + n) * 16 + l15];
    rg[n] = (f4){b, b, b, b};
  }
  {
    bf8 Wx[2], W[8];
#pragma unroll
    for (int n = 0; n < 2; ++n) Wx[n] = wi[((nt0 + n) * 3 + 1) * 64 + lane];
#pragma unroll
    for (int f = 0; f < 8; ++f)
      W[f] = wh[((nt0 + (f >> 2)) * 12 + 4 + (f & 3)) * 64 + lane];
#pragma unroll
    for (int n = 0; n < 2; ++n) rg[n] = MFMA(ax, Wx[n], rg[n]);
#pragma unroll
    for (int f = 0; f < 8; ++f) rg[f >> 2] = MFMA(ah[f & 3], W[f], rg[f >> 2]);
  }
  // h' = (1-z)*tanh(n) + z*h
#pragma unroll
  for (int n = 0; n < 2; ++n)
#pragma unroll
    for (int j = 0; j < 4; ++j) {
      const float hc = bf2f(hsrc[(q * 4 + j) * SH + (nt0 + n) * 16 + l15]);
      const float z = sigmoidf_(rg[n][j]);
      const float nn = tanhf_(t2[n][j]);
      hv[n][j] = (1.0f - z) * nn + z * hc;
    }
}

// pred = h@h2o + b; softmax; pred->global (nontemporal), probs->LDS. Wave 0 only.
__device__ __forceinline__ void pred_node(const short* hsrc,
                                          const short* h2oP,
                                          const float* __restrict__ h2ob,
                                          float* __restrict__ predout,
                                          short* pdst, int r0, int lane) {
  const int l15 = lane & 15, q = lane >> 4;
  bf8 a[4];
#pragma unroll
  for (int c = 0; c < 4; ++c)
    a[c] = *(const bf8*)(hsrc + l15 * SH + c * 32 + q * 8);
  const bf8* bo = (const bf8*)h2oP;
  bf8 W[8];
#pragma unroll
  for (int f = 0; f < 8; ++f) W[f] = bo[f * 64 + lane];
  f4 p[2];
#pragma unroll
  for (int nt = 0; nt < 2; ++nt) {
    const float b = h2ob[nt * 16 + l15];
    f4 acc = (f4){b, b, b, b};
#pragma unroll
    for (int c = 0; c < 4; ++c) acc = MFMA(a[c], W[nt * 4 + c], acc);
    p[nt] = acc;
  }
#pragma unroll
  for (int j = 0; j < 4; ++j) {
    const float v0 = p[0][j], v1 = p[1][j];
    float mx = fmaxf(v0, v1);
#pragma unroll
    for (int s = 1; s < 16; s <<= 1) mx = fmaxf(mx, __shfl_xor(mx, s));
    const float e0 = __expf(v0 - mx), e1 = __expf(v1 - mx);
    float ss = e0 + e1;
#pragma unroll
    for (int s = 1; s < 16; s <<= 1) ss += __shfl_xor(ss, s);
    const float inv = 1.0f / ss;
    const int row = q * 4 + j;
    __builtin_nontemporal_store(v0, predout + (size_t)(r0 + row) * OO + l15);
    __builtin_nontemporal_store(v1, predout + (size_t)(r0 + row) * OO + 16 + l15);
    pdst[row * PSLD + l15] = f2bf(e0 * inv);
    pdst[row * PSLD + 16 + l15] = f2bf(e1 * inv);
  }
}

// preorder schedule, depth 4: type 0=root, 1=left child (gru_a), 2=right child
__device__ const unsigned char d_TYPE[31] =
    {0,1,1,1,1,2,2,1,2,2,1,1,2,2,1,2,2,1,1,1,2,2,1,2,2,1,1,2,2,1,2};
__device__ const unsigned char d_LVL[31] =
    {0,1,2,3,4,4,3,4,4,2,3,4,4,3,4,4,1,2,3,4,4,3,4,4,2,3,4,4,3,4,4};

// ---------------- the fused tree kernel -------------------------------------
__global__ __launch_bounds__(256, 4) void k_tree(
    const short* __restrict__ zbf, const short* __restrict__ pw,
    const float* __restrict__ z2hb, const float* __restrict__ abi,
    const float* __restrict__ abh, const float* __restrict__ fbi,
    const float* __restrict__ fbh, const float* __restrict__ uab,
    const float* __restrict__ ufb, const float* __restrict__ h2ob,
    float* __restrict__ out) {
  __shared__ short hstk[5 * 16 * SH];
  __shared__ short hfb[16 * SH];
  __shared__ short pstk[5 * 16 * PSLD];
  const int lane = threadIdx.x & 63;
  const int w = threadIdx.x >> 6;
  const int l15 = lane & 15, q = lane >> 4;
  const int r0 = blockIdx.x * 16;

  // root: h_in[0] = z @ z2h + b (each wave computes its 32-col slice)
  {
    const bf8 az0 = *(const bf8*)(zbf + (size_t)(r0 + l15) * 64 + q * 8);
    const bf8 az1 = *(const bf8*)(zbf + (size_t)(r0 + l15) * 64 + 32 + q * 8);
    const bf8* wz = (const bf8*)(pw + PW_Z2H);
    bf8 W[4];
#pragma unroll
    for (int f = 0; f < 4; ++f)
      W[f] = wz[((2 * w + (f >> 1)) * 2 + (f & 1)) * 64 + lane];
    f4 hv[2];
#pragma unroll
    for (int n = 0; n < 2; ++n) {
      const float b = z2hb[(2 * w + n) * 16 + l15];
      f4 acc = (f4){b, b, b, b};
      acc = MFMA(az0, W[n * 2 + 0], acc);
      acc = MFMA(az1, W[n * 2 + 1], acc);
      hv[n] = acc;
    }
    store_slice(hv, hstk, lane, w);
  }
  __syncthreads();

#pragma unroll 1
  for (int i = 0; i < 31; ++i) {
    const int t = d_TYPE[i];
    const int L = d_LVL[i];
    short* hcur = hstk + L * 16 * SH;
    short* pcur = pstk + L * 16 * PSLD;

    if (t == 2) {
      // h_f = gru_f(probs_sib, h_sib)
      f4 hf[2];
      gru_slice(pcur, hcur, pw + PW_FWI, pw + PW_FWH, fbi, fbh, lane, w, hf);
      store_slice(hf, hfb, lane, w);
      __syncthreads();
      // h2 = tanh(h_f@uf + h_par@ua + b)
      const short* hpar = hstk + (L - 1) * 16 * SH;
      bf8 af[4], ap[4];
#pragma unroll
      for (int c = 0; c < 4; ++c) {
        af[c] = *(const bf8*)(hfb + l15 * SH + c * 32 + q * 8);
        ap[c] = *(const bf8*)(hpar + l15 * SH + c * 32 + q * 8);
      }
      const bf8* uf = (const bf8*)(pw + PW_UF);
      const bf8* ua = (const bf8*)(pw + PW_UA);
      bf8 Wf[8], Wa[8];
#pragma unroll
      for (int f = 0; f < 8; ++f) {
        Wf[f] = uf[((2 * w + (f >> 2)) * 4 + (f & 3)) * 64 + lane];
        Wa[f] = ua[((2 * w + (f >> 2)) * 4 + (f & 3)) * 64 + lane];
      }
      f4 hv[2];
#pragma unroll
      for (int n = 0; n < 2; ++n) {
        const float b = ufb[(2 * w + n) * 16 + l15] + uab[(2 * w + n) * 16 + l15];
        hv[n] = (f4){b, b, b, b};
      }
#pragma unroll
      for (int f = 0; f < 8; ++f) {
        hv[f >> 2] = MFMA(af[f & 3], Wf[f], hv[f >> 2]);
        hv[f >> 2] = MFMA(ap[f & 3], Wa[f], hv[f >> 2]);
      }
#pragma unroll
      for (int n = 0; n < 2; ++n)
#pragma unroll
        for (int j = 0; j < 4; ++j) hv[n][j] = tanhf_(hv[n][j]);
      store_slice(hv, hcur, lane, w);
      __syncthreads();
    }

    // pred + softmax (wave 0), probs -> pcur
    if (w == 0)
      pred_node(hcur, pw + PW_H2O, h2ob, out + (size_t)i * BB * OO, pcur, r0, lane);
    __syncthreads();

    // non-leaf: h_in[L+1] = gru_a(probs, h_in[L])
    if (L < 4) {
      f4 hv[2];
      gru_slice(pcur, hcur, pw + PW_AWI, pw + PW_AWH, abi, abh, lane, w, hv);
      store_slice(hv, hstk + (L + 1) * 16 * SH, lane, w);
      __syncthreads();
    }
  }
}

// ---------------- host ------------------------------------------------------
extern "C" void kernel_launch(void* const* d_in, const int* in_sizes, int n_in,
                              void* d_out, int out_size, void* d_ws, size_t ws_size,
                              hipStream_t stream) {
  const float* z    = (const float*)d_in[0];
  const float* z2hw = (const float*)d_in[1];
  const float* z2hb = (const float*)d_in[2];
  const float* h2ow = (const float*)d_in[3];
  const float* h2ob = (const float*)d_in[4];
  const float* awi  = (const float*)d_in[5];
  const float* abi  = (const float*)d_in[6];
  const float* awh  = (const float*)d_in[7];
  const float* abh  = (const float*)d_in[8];
  const float* fwi  = (const float*)d_in[9];
  const float* fbi  = (const float*)d_in[10];
  const float* fwh  = (const float*)d_in[11];
  const float* fbh  = (const float*)d_in[12];
  const float* uaw  = (const float*)d_in[13];
  const float* uab  = (const float*)d_in[14];
  const float* ufw  = (const float*)d_in[15];
  const float* ufb  = (const float*)d_in[16];

  float* out = (float*)d_out;
  short* ws  = (short*)d_ws;

  const int total = PW_END + BB * 64;
  k_repack<<<(total + 255) / 256, 256, 0, stream>>>(
      z2hw, awi, awh, fwi, fwh, uaw, ufw, h2ow, z, ws);

  k_tree<<<BB / 16, 256, 0, stream>>>(
      ws + ZBF, ws, z2hb, abi, abh, fbi, fbh, uab, ufb, h2ob, out);
}

// Round 7
// 338.960 us; speedup vs baseline: 5.0563x; 1.6380x over previous
//
#include <hip/hip_runtime.h>
#include <cstddef>

// HVAE tree decoder, fused single kernel. Block = 256 thr (4 waves) = 32 batch
// rows (2 row-tiles of 16); each wave owns a 32-col slice (2 nt-tiles) of N=128.
// Every B-fragment load feeds 2 MFMAs (M=32) -> half the weight traffic of M=16.
// h/probs stacks in LDS; pred staged in LDS (overlaid on hfb) and dumped as
// contiguous nontemporal float4 (full 128B lines). Grid = B/32 = 512.

#define BB   16384
#define HH   128
#define OO   32

typedef __attribute__((ext_vector_type(8))) short bf8;
typedef __attribute__((ext_vector_type(4))) float f4;

#define MFMA(a, b, c) __builtin_amdgcn_mfma_f32_16x16x32_bf16(a, b, c, 0, 0, 0)

// packed-weight offsets in ws (shorts)
#define PW_Z2H 0         // [64x128]  -> 8192
#define PW_AWI 8192      // [96x128]  -> 12288
#define PW_AWH 20480     // [384x128] -> 49152
#define PW_FWI 69632     // [96x128]  -> 12288
#define PW_FWH 81920     // [384x128] -> 49152
#define PW_UA  131072    // [128x128] -> 16384
#define PW_UF  147456    // [128x128] -> 16384
#define PW_H2O 163840    // [128x32]  -> 4096
#define PW_END 167936
#define ZBF    167936    // B*64 bf16

#define SH   136   // LDS h row stride (shorts): 272B rows, 16B aligned, depads banks
#define PSLD 40    // LDS probs row stride (shorts)

__device__ __forceinline__ short f2bf(float f) {
  union { float f; unsigned u; } v; v.f = f;
  unsigned r = v.u + 0x7fff + ((v.u >> 16) & 1);   // RNE
  return (short)(r >> 16);
}
__device__ __forceinline__ float bf2f(short h) {
  union { unsigned u; float f; } v;
  v.u = ((unsigned)(unsigned short)h) << 16;
  return v.f;
}
__device__ __forceinline__ float sigmoidf_(float x) { return 1.0f / (1.0f + __expf(-x)); }
__device__ __forceinline__ float tanhf_(float x) {
  float ax = fabsf(x), e = __expf(-2.0f * ax), t = (1.0f - e) / (1.0f + e);
  return x >= 0.0f ? t : -t;
}

// ---------------- repack: fp32 [K][N] -> B-frag-major bf16 -------------------
// P[((nt*KC + kc)*64 + lane)*8 + j] = W[kc*32 + (lane>>4)*8 + j][nt*16 + (lane&15)]
template <int K, int N>
__device__ __forceinline__ void repack_one(const float* __restrict__ W,
                                           short* __restrict__ P, int idx) {
  const int KC = K / 32;
  const int j = idx & 7, lane = (idx >> 3) & 63, rest = idx >> 9;
  const int kc = rest % KC, nt = rest / KC;
  const int k = kc * 32 + ((lane >> 4) << 3) + j;
  const int n = nt * 16 + (lane & 15);
  P[idx] = f2bf(W[(size_t)k * N + n]);
}

__global__ __launch_bounds__(256) void k_repack(
    const float* __restrict__ z2hw, const float* __restrict__ awi,
    const float* __restrict__ awh, const float* __restrict__ fwi,
    const float* __restrict__ fwh, const float* __restrict__ uaw,
    const float* __restrict__ ufw, const float* __restrict__ h2ow,
    const float* __restrict__ z, short* __restrict__ ws) {
  const int t = blockIdx.x * 256 + threadIdx.x;
  if (t < PW_AWI)        repack_one<64, 128>(z2hw, ws + PW_Z2H, t - PW_Z2H);
  else if (t < PW_AWH)   repack_one<96, 128>(awi, ws + PW_AWI, t - PW_AWI);
  else if (t < PW_FWI)   repack_one<384, 128>(awh, ws + PW_AWH, t - PW_AWH);
  else if (t < PW_FWH)   repack_one<96, 128>(fwi, ws + PW_FWI, t - PW_FWI);
  else if (t < PW_UA)    repack_one<384, 128>(fwh, ws + PW_FWH, t - PW_FWH);
  else if (t < PW_UF)    repack_one<128, 128>(uaw, ws + PW_UA, t - PW_UA);
  else if (t < PW_H2O)   repack_one<128, 128>(ufw, ws + PW_UF, t - PW_UF);
  else if (t < PW_END)   repack_one<128, 32>(h2ow, ws + PW_H2O, t - PW_H2O);
  else {
    const int i = t - PW_END;
    if (i < BB * 64) ws[ZBF + i] = f2bf(z[i]);
  }
}

// ---------------- slice helpers (wave w owns nt tiles 2w,2w+1; rt = row-tile) -
// hv index: rt*2 + n
__device__ __forceinline__ void store_slice32(const f4* hv, short* dst, int lane, int w) {
  const int l15 = lane & 15, q = lane >> 4;
#pragma unroll
  for (int rt = 0; rt < 2; ++rt)
#pragma unroll
    for (int n = 0; n < 2; ++n)
#pragma unroll
      for (int j = 0; j < 4; ++j)
        dst[(rt * 16 + q * 4 + j) * SH + (2 * w + n) * 16 + l15] =
            f2bf(hv[rt * 2 + n][j]);
}

// GRU slice over 2 row-tiles: x from LDS probs block, h from LDS h block.
__device__ __forceinline__ void gru_slice32(const short* xs, const short* hsrc,
                                            const short* wiP, const short* whP,
                                            const float* __restrict__ bi,
                                            const float* __restrict__ bh,
                                            int lane, int w, f4* hv) {
  const int l15 = lane & 15, q = lane >> 4;
  const int nt0 = 2 * w;
  bf8 ax[2], ah[2][4];
#pragma unroll
  for (int rt = 0; rt < 2; ++rt) {
    ax[rt] = *(const bf8*)(xs + (rt * 16 + l15) * PSLD + q * 8);
#pragma unroll
    for (int c = 0; c < 4; ++c)
      ah[rt][c] = *(const bf8*)(hsrc + (rt * 16 + l15) * SH + c * 32 + q * 8);
  }
  const bf8* wi = (const bf8*)wiP;
  const bf8* wh = (const bf8*)whP;
  f4 t2[4], rg[4];
  // t2 = bh2 + h@wh2
#pragma unroll
  for (int rt = 0; rt < 2; ++rt)
#pragma unroll
    for (int n = 0; n < 2; ++n) {
      const float b = bh[2 * HH + (nt0 + n) * 16 + l15];
      t2[rt * 2 + n] = (f4){b, b, b, b};
    }
  {
    bf8 W[8];
#pragma unroll
    for (int f = 0; f < 8; ++f)
      W[f] = wh[((nt0 + (f >> 2)) * 12 + 8 + (f & 3)) * 64 + lane];
#pragma unroll
    for (int f = 0; f < 8; ++f)
#pragma unroll
      for (int rt = 0; rt < 2; ++rt)
        t2[rt * 2 + (f >> 2)] = MFMA(ah[rt][f & 3], W[f], t2[rt * 2 + (f >> 2)]);
  }
  // r gate
#pragma unroll
  for (int rt = 0; rt < 2; ++rt)
#pragma unroll
    for (int n = 0; n < 2; ++n) {
      const float b = bi[(nt0 + n) * 16 + l15] + bh[(nt0 + n) * 16 + l15];
      rg[rt * 2 + n] = (f4){b, b, b, b};
    }
  {
    bf8 Wx[2], W[8];
#pragma unroll
    for (int n = 0; n < 2; ++n) Wx[n] = wi[((nt0 + n) * 3 + 0) * 64 + lane];
#pragma unroll
    for (int f = 0; f < 8; ++f)
      W[f] = wh[((nt0 + (f >> 2)) * 12 + 0 + (f & 3)) * 64 + lane];
#pragma unroll
    for (int rt = 0; rt < 2; ++rt)
#pragma unroll
      for (int n = 0; n < 2; ++n)
        rg[rt * 2 + n] = MFMA(ax[rt], Wx[n], rg[rt * 2 + n]);
#pragma unroll
    for (int f = 0; f < 8; ++f)
#pragma unroll
      for (int rt = 0; rt < 2; ++rt)
        rg[rt * 2 + (f >> 2)] = MFMA(ah[rt][f & 3], W[f], rg[rt * 2 + (f >> 2)]);
  }
#pragma unroll
  for (int k = 0; k < 4; ++k)
#pragma unroll
    for (int j = 0; j < 4; ++j) t2[k][j] *= sigmoidf_(rg[k][j]);  // r*(h@wh2+bh2)
  // n preact completes in t2
#pragma unroll
  for (int rt = 0; rt < 2; ++rt)
#pragma unroll
    for (int n = 0; n < 2; ++n) {
      const float b = bi[2 * HH + (nt0 + n) * 16 + l15];
#pragma unroll
      for (int j = 0; j < 4; ++j) t2[rt * 2 + n][j] += b;
    }
  {
    bf8 Wx[2];
#pragma unroll
    for (int n = 0; n < 2; ++n) Wx[n] = wi[((nt0 + n) * 3 + 2) * 64 + lane];
#pragma unroll
    for (int rt = 0; rt < 2; ++rt)
#pragma unroll
      for (int n = 0; n < 2; ++n)
        t2[rt * 2 + n] = MFMA(ax[rt], Wx[n], t2[rt * 2 + n]);
  }
  // z gate
#pragma unroll
  for (int rt = 0; rt < 2; ++rt)
#pragma unroll
    for (int n = 0; n < 2; ++n) {
      const float b = bi[HH + (nt0 + n) * 16 + l15] + bh[HH + (nt0 + n) * 16 + l15];
      rg[rt * 2 + n] = (f4){b, b, b, b};
    }
  {
    bf8 Wx[2], W[8];
#pragma unroll
    for (int n = 0; n < 2; ++n) Wx[n] = wi[((nt0 + n) * 3 + 1) * 64 + lane];
#pragma unroll
    for (int f = 0; f < 8; ++f)
      W[f] = wh[((nt0 + (f >> 2)) * 12 + 4 + (f & 3)) * 64 + lane];
#pragma unroll
    for (int rt = 0; rt < 2; ++rt)
#pragma unroll
      for (int n = 0; n < 2; ++n)
        rg[rt * 2 + n] = MFMA(ax[rt], Wx[n], rg[rt * 2 + n]);
#pragma unroll
    for (int f = 0; f < 8; ++f)
#pragma unroll
      for (int rt = 0; rt < 2; ++rt)
        rg[rt * 2 + (f >> 2)] = MFMA(ah[rt][f & 3], W[f], rg[rt * 2 + (f >> 2)]);
  }
  // h' = (1-z)*tanh(n) + z*h
#pragma unroll
  for (int rt = 0; rt < 2; ++rt)
#pragma unroll
    for (int n = 0; n < 2; ++n)
#pragma unroll
      for (int j = 0; j < 4; ++j) {
        const float hc =
            bf2f(hsrc[(rt * 16 + q * 4 + j) * SH + (nt0 + n) * 16 + l15]);
        const float z = sigmoidf_(rg[rt * 2 + n][j]);
        const float nn = tanhf_(t2[rt * 2 + n][j]);
        hv[rt * 2 + n][j] = (1.0f - z) * nn + z * hc;
      }
}

// pred for row-tile w (waves 0,1 only): pred = h@h2o + b; softmax;
// pred -> LDS spred (fp32), probs -> LDS pstk.
__device__ __forceinline__ void pred_node32(const short* hsrc,
                                            const short* h2oP,
                                            const float* __restrict__ h2ob,
                                            float* spred, short* pdst,
                                            int lane, int w) {
  const int l15 = lane & 15, q = lane >> 4;
  bf8 a[4];
#pragma unroll
  for (int c = 0; c < 4; ++c)
    a[c] = *(const bf8*)(hsrc + (w * 16 + l15) * SH + c * 32 + q * 8);
  const bf8* bo = (const bf8*)h2oP;
  bf8 W[8];
#pragma unroll
  for (int f = 0; f < 8; ++f) W[f] = bo[f * 64 + lane];
  f4 p[2];
#pragma unroll
  for (int nt = 0; nt < 2; ++nt) {
    const float b = h2ob[nt * 16 + l15];
    f4 acc = (f4){b, b, b, b};
#pragma unroll
    for (int c = 0; c < 4; ++c) acc = MFMA(a[c], W[nt * 4 + c], acc);
    p[nt] = acc;
  }
#pragma unroll
  for (int j = 0; j < 4; ++j) {
    const float v0 = p[0][j], v1 = p[1][j];
    float mx = fmaxf(v0, v1);
#pragma unroll
    for (int s = 1; s < 16; s <<= 1) mx = fmaxf(mx, __shfl_xor(mx, s));
    const float e0 = __expf(v0 - mx), e1 = __expf(v1 - mx);
    float ss = e0 + e1;
#pragma unroll
    for (int s = 1; s < 16; s <<= 1) ss += __shfl_xor(ss, s);
    const float inv = 1.0f / ss;
    const int row = w * 16 + q * 4 + j;
    spred[row * 32 + l15] = v0;
    spred[row * 32 + 16 + l15] = v1;
    pdst[row * PSLD + l15] = f2bf(e0 * inv);
    pdst[row * PSLD + 16 + l15] = f2bf(e1 * inv);
  }
}

// preorder schedule, depth 4: type 0=root, 1=left child (gru_a), 2=right child
__device__ const unsigned char d_TYPE[31] =
    {0,1,1,1,1,2,2,1,2,2,1,1,2,2,1,2,2,1,1,1,2,2,1,2,2,1,1,2,2,1,2};
__device__ const unsigned char d_LVL[31] =
    {0,1,2,3,4,4,3,4,4,2,3,4,4,3,4,4,1,2,3,4,4,3,4,4,2,3,4,4,3,4,4};

// ---------------- the fused tree kernel -------------------------------------
__global__ __launch_bounds__(256, 2) void k_tree(
    const short* __restrict__ zbf, const short* __restrict__ pw,
    const float* __restrict__ z2hb, const float* __restrict__ abi,
    const float* __restrict__ abh, const float* __restrict__ fbi,
    const float* __restrict__ fbh, const float* __restrict__ uab,
    const float* __restrict__ ufb, const float* __restrict__ h2ob,
    float* __restrict__ out) {
  __shared__ __align__(16) short hstk[5 * 32 * SH];   // 43520 B
  __shared__ __align__(16) short hfb[32 * SH];        // 8704 B (overlaid: spred)
  __shared__ __align__(16) short pstk[5 * 32 * PSLD]; // 12800 B  => 65024 B total
  float* spred = (float*)hfb;                         // 4096 B, lifetime-disjoint
  const int lane = threadIdx.x & 63;
  const int w = threadIdx.x >> 6;
  const int l15 = lane & 15, q = lane >> 4;
  const int r0 = blockIdx.x * 32;

  // root: h_in[0] = z @ z2h + b (each wave: its 32-col slice, both row-tiles)
  {
    const bf8* wz = (const bf8*)(pw + PW_Z2H);
    bf8 W[4];
#pragma unroll
    for (int f = 0; f < 4; ++f)
      W[f] = wz[((2 * w + (f >> 1)) * 2 + (f & 1)) * 64 + lane];
    f4 hv[4];
#pragma unroll
    for (int rt = 0; rt < 2; ++rt) {
      const bf8 az0 = *(const bf8*)(zbf + (size_t)(r0 + rt * 16 + l15) * 64 + q * 8);
      const bf8 az1 = *(const bf8*)(zbf + (size_t)(r0 + rt * 16 + l15) * 64 + 32 + q * 8);
#pragma unroll
      for (int n = 0; n < 2; ++n) {
        const float b = z2hb[(2 * w + n) * 16 + l15];
        f4 acc = (f4){b, b, b, b};
        acc = MFMA(az0, W[n * 2 + 0], acc);
        acc = MFMA(az1, W[n * 2 + 1], acc);
        hv[rt * 2 + n] = acc;
      }
    }
    store_slice32(hv, hstk, lane, w);
  }
  __syncthreads();

#pragma unroll 1
  for (int i = 0; i < 31; ++i) {
    const int t = d_TYPE[i];
    const int L = d_LVL[i];
    short* hcur = hstk + L * 32 * SH;
    short* pcur = pstk + L * 32 * PSLD;

    if (t == 2) {
      // h_f = gru_f(probs_sib, h_sib)
      f4 hf[4];
      gru_slice32(pcur, hcur, pw + PW_FWI, pw + PW_FWH, fbi, fbh, lane, w, hf);
      store_slice32(hf, hfb, lane, w);
      __syncthreads();
      // h2 = tanh(h_f@uf + h_par@ua + b)
      const short* hpar = hstk + (L - 1) * 32 * SH;
      bf8 af[2][4], ap[2][4];
#pragma unroll
      for (int rt = 0; rt < 2; ++rt)
#pragma unroll
        for (int c = 0; c < 4; ++c) {
          af[rt][c] = *(const bf8*)(hfb + (rt * 16 + l15) * SH + c * 32 + q * 8);
          ap[rt][c] = *(const bf8*)(hpar + (rt * 16 + l15) * SH + c * 32 + q * 8);
        }
      const bf8* uf = (const bf8*)(pw + PW_UF);
      const bf8* ua = (const bf8*)(pw + PW_UA);
      bf8 Wf[8], Wa[8];
#pragma unroll
      for (int f = 0; f < 8; ++f) {
        Wf[f] = uf[((2 * w + (f >> 2)) * 4 + (f & 3)) * 64 + lane];
        Wa[f] = ua[((2 * w + (f >> 2)) * 4 + (f & 3)) * 64 + lane];
      }
      f4 hv[4];
#pragma unroll
      for (int rt = 0; rt < 2; ++rt)
#pragma unroll
        for (int n = 0; n < 2; ++n) {
          const float b = ufb[(2 * w + n) * 16 + l15] + uab[(2 * w + n) * 16 + l15];
          hv[rt * 2 + n] = (f4){b, b, b, b};
        }
#pragma unroll
      for (int f = 0; f < 8; ++f)
#pragma unroll
        for (int rt = 0; rt < 2; ++rt) {
          hv[rt * 2 + (f >> 2)] = MFMA(af[rt][f & 3], Wf[f], hv[rt * 2 + (f >> 2)]);
          hv[rt * 2 + (f >> 2)] = MFMA(ap[rt][f & 3], Wa[f], hv[rt * 2 + (f >> 2)]);
        }
#pragma unroll
      for (int k = 0; k < 4; ++k)
#pragma unroll
        for (int j = 0; j < 4; ++j) hv[k][j] = tanhf_(hv[k][j]);
      store_slice32(hv, hcur, lane, w);
      __syncthreads();
    }

    // pred + softmax: waves 0,1 each handle one 16-row tile
    if (w < 2)
      pred_node32(hcur, pw + PW_H2O, h2ob, spred, pcur, lane, w);
    __syncthreads();

    // dump pred: 32 rows x 32 cols fp32 = 4KB contiguous, all 256 threads
    {
      const f4 v = *(const f4*)(spred + threadIdx.x * 4);
      __builtin_nontemporal_store(
          v, (f4*)(out + (size_t)i * BB * OO + (size_t)r0 * OO) + threadIdx.x);
    }

    // non-leaf: h_in[L+1] = gru_a(probs, h_in[L])
    if (L < 4) {
      f4 hv[4];
      gru_slice32(pcur, hcur, pw + PW_AWI, pw + PW_AWH, abi, abh, lane, w, hv);
      store_slice32(hv, hstk + (L + 1) * 32 * SH, lane, w);
    }
    // barrier also protects spred (overlaid on hfb) against next node's writes
    __syncthreads();
  }
}

// ---------------- host ------------------------------------------------------
extern "C" void kernel_launch(void* const* d_in, const int* in_sizes, int n_in,
                              void* d_out, int out_size, void* d_ws, size_t ws_size,
                              hipStream_t stream) {
  const float* z    = (const float*)d_in[0];
  const float* z2hw = (const float*)d_in[1];
  const float* z2hb = (const float*)d_in[2];
  const float* h2ow = (const float*)d_in[3];
  const float* h2ob = (const float*)d_in[4];
  const float* awi  = (const float*)d_in[5];
  const float* abi  = (const float*)d_in[6];
  const float* awh  = (const float*)d_in[7];
  const float* abh  = (const float*)d_in[8];
  const float* fwi  = (const float*)d_in[9];
  const float* fbi  = (const float*)d_in[10];
  const float* fwh  = (const float*)d_in[11];
  const float* fbh  = (const float*)d_in[12];
  const float* uaw  = (const float*)d_in[13];
  const float* uab  = (const float*)d_in[14];
  const float* ufw  = (const float*)d_in[15];
  const float* ufb  = (const float*)d_in[16];

  float* out = (float*)d_out;
  short* ws  = (short*)d_ws;

  const int total = PW_END + BB * 64;
  k_repack<<<(total + 255) / 256, 256, 0, stream>>>(
      z2hw, awi, awh, fwi, fwh, uaw, ufw, h2ow, z, ws);

  k_tree<<<BB / 32, 256, 0, stream>>>(
      ws + ZBF, ws, z2hb, abi, abh, fbi, fbh, uab, ufb, h2ob, out);
}